// Round 18
// baseline (638.759 us; speedup 1.0000x reference)
//
#include <hip/hip_runtime.h>
#include <hip/hip_bf16.h>
#include <math.h>

#define SSH 4
#define SCALE 0.17677669529663687f  // 1/sqrt(32)

typedef __bf16 bf16x8 __attribute__((ext_vector_type(8)));
typedef __bf16 bf16x4 __attribute__((ext_vector_type(4)));
typedef unsigned short ushort8 __attribute__((ext_vector_type(8)));
typedef float  f32x4  __attribute__((ext_vector_type(4)));

static __device__ __forceinline__ f32x4 mfma16(bf16x8 a, bf16x8 b, f32x4 c){
    return __builtin_amdgcn_mfma_f32_16x16x32_bf16(a, b, c, 0, 0, 0);
}
#define MFMA16(a,b,c) mfma16((a),(b),(c))

static __device__ __forceinline__ bf16x8 ldfrag(const __bf16* p){
    return *reinterpret_cast<const bf16x8*>(p);
}
static __device__ __forceinline__ f32x4 zero4(){
    f32x4 z; z[0]=0.f; z[1]=0.f; z[2]=0.f; z[3]=0.f; return z;
}
// tanh-form GELU via sigmoid identity: 0.5x(1+tanh(u)) == x * sigma(2u)
static __device__ __forceinline__ float gelu_fast(float x){
    float u = x*(0.7978845608f + 0.0356774081f*x*x);
    return __fdividef(x, 1.f + __expf(-2.f*u));
}

// ---------------- K0: weight prep (bf16 [N][K]) + Fourier constant tables ----
__global__ __launch_bounds__(256) void k_prep(const float* __restrict__ qkvw,
        const float* __restrict__ projw, const float* __restrict__ fc1w,
        const float* __restrict__ fc2w, __bf16* __restrict__ Wq,
        __bf16* __restrict__ Wp, __bf16* __restrict__ W1, __bf16* __restrict__ W2,
        __bf16* __restrict__ Fre, __bf16* __restrict__ Fim,
        __bf16* __restrict__ Ci,  __bf16* __restrict__ nSi){
    int i = blockIdx.x*256 + threadIdx.x;
    if (i < 110592){ int n = i/192, k = i - n*192; Wq[i] = (__bf16)qkvw[k*576 + n]; }
    if (i < 36864) { int n = i/192, k = i - n*192; Wp[i] = (__bf16)projw[k*192 + n]; }
    if (i < 147456){ int n = i/192, k = i - n*192; W1[i] = (__bf16)fc1w[k*768 + n]; }
    if (i < 147456){ int n = i/768, k = i - n*768; W2[i] = (__bf16)fc2w[k*192 + n]; }
    if (i < 3072){
        int n = i>>6, p = i&63;
        float vr = 0.f, vi = 0.f;
        if (n < 40){
            int u = n/5, v = n - u*5, r = p>>3, c = p&7;
            int k = (u*r + v*c)&7;
            float ang = (float)k * 0.78539816339744831f;
            vr = cosf(ang)*0.125f; vi = -sinf(ang)*0.125f;
        }
        Fre[i] = (__bf16)vr; Fim[i] = (__bf16)vi;
    }
    if (i < 4096){
        int p = i>>6, n = i&63;
        float vc = 0.f, vs = 0.f;
        if (n < 40){
            int u = n/5, v = n - u*5, r = p>>3, c = p&7;
            int k = (u*r + v*c)&7;
            float ang = (float)k * 0.78539816339744831f;
            float wv = (v>=1 && v<=3)? 2.f : 1.f;
            vc = wv*cosf(ang)*0.125f; vs = -wv*sinf(ang)*0.125f;
        }
        Ci[i] = (__bf16)vc; nSi[i] = (__bf16)vs;
    }
}

// ---------------- K1: LN1 + shift + qkv GEMM (MFMA, staged W + coalesced S) --
__global__ __launch_bounds__(256,2) void k_qkv(const float* __restrict__ x,
        const float* __restrict__ n1g, const float* __restrict__ n1b,
        const __bf16* __restrict__ Wqt, const float* __restrict__ qkv_b,
        __bf16* __restrict__ S){
    __shared__ __align__(16) __bf16 xw[64*200];
    __shared__ __align__(16) __bf16 Wt[192*72];
    __shared__ __align__(16) __bf16 Ss[64*200];
    int tid = threadIdx.x;
    int win = blockIdx.x;
    int bb = win>>8, rem = win&255, wh = rem>>4, wwi = rem&15;
    {
        int tok = tid>>2, part = tid&3;
        int r = tok>>3, c = tok&7;
        int sh = (wh*8 + r + SSH)&127, sw = (wwi*8 + c + SSH)&127;
        const float* srcp = x + (((size_t)(bb*128+sh))*128 + sw)*192 + part*48;
        float v[48];
        #pragma unroll
        for (int i=0;i<12;i++){
            float4 t4 = *reinterpret_cast<const float4*>(srcp + i*4);
            v[i*4]=t4.x; v[i*4+1]=t4.y; v[i*4+2]=t4.z; v[i*4+3]=t4.w;
        }
        float s=0.f, ss=0.f;
        #pragma unroll
        for (int i=0;i<48;i++){ s+=v[i]; ss+=v[i]*v[i]; }
        s  += __shfl_xor(s,1);  s  += __shfl_xor(s,2);
        ss += __shfl_xor(ss,1); ss += __shfl_xor(ss,2);
        float mean = s*(1.f/192.f);
        float rstd = rsqrtf(ss*(1.f/192.f) - mean*mean + 1e-5f);
        #pragma unroll
        for (int i8=0;i8<6;i8++){
            bf16x8 pk;
            #pragma unroll
            for (int j=0;j<8;j++){
                int ch = part*48 + i8*8 + j;
                pk[j] = (__bf16)((v[i8*8+j]-mean)*rstd*n1g[ch] + n1b[ch]);
            }
            *reinterpret_cast<bf16x8*>(&xw[tok*200 + part*48 + i8*8]) = pk;
        }
    }
    int lane = tid&63, w = tid>>6, lr = lane&15, lg = lane>>4;
    ushort8 wreg[6];
    auto ldW = [&](int s, ushort8* wr){
        int nc = s/3, kc = s - nc*3;
        #pragma unroll
        for (int i=0;i<6;i++){
            int e = tid + i*256;
            int j = e>>3, k8 = e&7;
            wr[i] = *reinterpret_cast<const ushort8*>(
                reinterpret_cast<const unsigned short*>(Wqt) + (size_t)(nc*192+j)*192 + kc*64 + k8*8);
        }
    };
    auto stW = [&](ushort8* wr){
        #pragma unroll
        for (int i=0;i<6;i++){
            int e = tid + i*256;
            int j = e>>3, k8 = e&7;
            *reinterpret_cast<ushort8*>(reinterpret_cast<unsigned short*>(Wt) + j*72 + k8*8) = wr[i];
        }
    };
    ldW(0, wreg);
    __syncthreads();
    stW(wreg);
    __syncthreads();
    f32x4 acc[4][3];
    #pragma unroll
    for (int m=0;m<4;m++)
        #pragma unroll
        for (int n=0;n<3;n++) acc[m][n] = zero4();
    for (int s=0; s<9; s++){
        int nc = s/3, kc = s - nc*3;
        if (s<8) ldW(s+1, wreg);
        #pragma unroll
        for (int kk=0; kk<2; kk++){
            int ko = kc*64 + kk*32 + lg*8;
            bf16x8 a[4];
            #pragma unroll
            for (int m=0;m<4;m++) a[m] = ldfrag(&xw[(16*m+lr)*200 + ko]);
            int klo = kk*32 + lg*8;
            bf16x8 bfr[3];
            #pragma unroll
            for (int n=0;n<3;n++) bfr[n] = ldfrag(&Wt[(48*w+16*n+lr)*72 + klo]);
            #pragma unroll
            for (int m=0;m<4;m++)
                #pragma unroll
                for (int n=0;n<3;n++) acc[m][n] = MFMA16(a[m], bfr[n], acc[m][n]);
        }
        if (kc==2){
            #pragma unroll
            for (int n=0;n<3;n++){
                int colL = 48*w + 16*n + lr;
                float bias = qkv_b[nc*192 + colL];
                #pragma unroll
                for (int m=0;m<4;m++)
                    #pragma unroll
                    for (int r=0;r<4;r++){
                        Ss[(16*m + 4*lg + r)*200 + colL] = (__bf16)(acc[m][n][r] + bias);
                        acc[m][n][r] = 0.f;
                    }
            }
        }
        __syncthreads();
        if (kc==2){
            #pragma unroll
            for (int i=0;i<6;i++){
                int e = tid + i*256;
                int row = e/24, c8 = e - row*24;
                *reinterpret_cast<bf16x8*>(S + (size_t)(win*64+row)*576 + nc*192 + c8*8) =
                    *reinterpret_cast<const bf16x8*>(&Ss[row*200 + c8*8]);
            }
        }
        if (s<8) stW(wreg);
        __syncthreads();
    }
}

// ------- K2: heterogeneous attention launch: blocks [0,12288) = fourier->Fb,
//         blocks [12288,14336) = spatial->Bb. Independent, run concurrently. --
__global__ __launch_bounds__(256,3) void k_attn2(const __bf16* __restrict__ S,
        const float* __restrict__ relt, const float* __restrict__ mask,
        const float* __restrict__ qkv_b,
        const __bf16* __restrict__ Fre_g, const __bf16* __restrict__ Fim_g,
        const __bf16* __restrict__ Ci_g,  const __bf16* __restrict__ nSi_g,
        __bf16* __restrict__ Bb, __bf16* __restrict__ Fb){
    __shared__ __align__(16) unsigned char arena[51968];
    int tid = threadIdx.x;
    int bid = blockIdx.x;
    int lane = tid&63, w = tid>>6, lr = lane&15, lg = lane>>4;
    bf16x4 z4; z4[0]=z4[1]=z4[2]=z4[3]=(__bf16)0.f;
    if (bid < 12288){
        // =================== fourier path ===================
        __bf16* Gq_r = (__bf16*)(arena);             // [48][40]
        __bf16* Gqin = (__bf16*)(arena + 3840);
        __bf16* Gk_r = (__bf16*)(arena + 7680);
        __bf16* Gk_i = (__bf16*)(arena + 11520);
        __bf16* Rt_r = (__bf16*)(arena);             // [32][88] overlay
        __bf16* Rt_i = (__bf16*)(arena + 5632);
        __bf16* Gv_r = (__bf16*)(arena + 15360);
        __bf16* Gv_i = (__bf16*)(arena + 20992);
        __bf16* St3  = (__bf16*)(arena + 26624);     // [3][32][88]
        float*  Smat = (float*) (arena + 26624);     // [48][52] overlay
        __bf16* P    = (__bf16*)(arena + 43520);     // [48][88]
        int win = bid / 6, h = bid - win*6;
        const size_t sbase = (size_t)win*64*576 + h*32;
        {
            int t2 = tid & 127;
            __bf16* A = (tid<128)? Gv_r : Gv_i;
            int row = t2>>2, c4 = (t2&3)*4;
            *reinterpret_cast<bf16x4*>(A + row*88 + 48 + c4) = z4;
        }
        {
            int d = tid&31, pg = tid>>5;
            #pragma unroll
            for (int m=0;m<3;m++){
                const __bf16* sp = S + sbase + (size_t)m*192 + (size_t)pg*8*576 + d;
                bf16x4 v0, v1;
                v0[0]=sp[0];      v0[1]=sp[576];    v0[2]=sp[1152];   v0[3]=sp[1728];
                v1[0]=sp[2304];   v1[1]=sp[2880];   v1[2]=sp[3456];   v1[3]=sp[4032];
                *reinterpret_cast<bf16x4*>(&St3[m*2816 + d*88 + pg*8])     = v0;
                *reinterpret_cast<bf16x4*>(&St3[m*2816 + d*88 + pg*8 + 4]) = v1;
            }
        }
        __syncthreads();
        for (int j=w; j<36; j+=4){
            int m = j/12, jj = j - m*12;
            int term = jj/6, r2 = jj - term*6;
            const __bf16* Stm = &St3[m*2816];
            if (m<2){
                int mt = r2>>1, nt = r2&1;
                const __bf16* Ag = (term? Fim_g : Fre_g) + (16*mt+lr)*64 + lg*8;
                f32x4 acc = zero4();
                acc = MFMA16(*reinterpret_cast<const bf16x8*>(Ag),
                             ldfrag(&Stm[(16*nt+lr)*88 + lg*8]), acc);
                acc = MFMA16(*reinterpret_cast<const bf16x8*>(Ag+32),
                             ldfrag(&Stm[(16*nt+lr)*88 + 32 + lg*8]), acc);
                int d = 16*nt + lr;
                float b = qkv_b[m*192 + h*32 + d];
                __bf16* dst = (m==0)? (term? Gqin : Gq_r) : (term? Gk_i : Gk_r);
                #pragma unroll
                for (int r=0;r<4;r++){
                    int n = 16*mt + 4*lg + r;
                    float val = acc[r] + ((term==0) ? ((n==0)? -7.f*b : b) : b);
                    if (m==0 && term==1) val = -val;     // store -Qi
                    dst[n*40 + d] = (__bf16)val;
                }
            } else {
                int mt = r2/3, nt = r2 - mt*3;
                const __bf16* Bg = (term? Fim_g : Fre_g) + (16*nt+lr)*64 + lg*8;
                f32x4 acc = zero4();
                acc = MFMA16(ldfrag(&Stm[(16*mt+lr)*88 + lg*8]),
                             *reinterpret_cast<const bf16x8*>(Bg), acc);
                acc = MFMA16(ldfrag(&Stm[(16*mt+lr)*88 + 32 + lg*8]),
                             *reinterpret_cast<const bf16x8*>(Bg+32), acc);
                int n = 16*nt + lr;
                __bf16* dst = term? Gv_i : Gv_r;
                #pragma unroll
                for (int r=0;r<4;r++){
                    int d = 16*mt + 4*lg + r;
                    float b = qkv_b[2*192 + h*32 + d];
                    float val = acc[r] + ((term==0) ? ((n==0)? -7.f*b : b) : b);
                    dst[d*88 + n] = (__bf16)val;
                }
            }
        }
        __syncthreads();
        for (int j=w; j<9; j+=4){
            int mt = j/3, nt = j - mt*3;
            bf16x8 qr = ldfrag(&Gq_r[(16*mt+lr)*40 + lg*8]);
            bf16x8 qi = ldfrag(&Gqin[(16*mt+lr)*40 + lg*8]);
            bf16x8 kr = ldfrag(&Gk_r[(16*nt+lr)*40 + lg*8]);
            bf16x8 ki = ldfrag(&Gk_i[(16*nt+lr)*40 + lg*8]);
            f32x4 sre = MFMA16(qi, ki, zero4());   // (-Qi).Ki
            sre = MFMA16(qr, kr, sre);             // + Qr.Kr
            f32x4 t1 = MFMA16(qr, ki, zero4());    // Qr.Ki
            f32x4 t2 = MFMA16(qi, kr, zero4());    // (-Qi).Kr
            #pragma unroll
            for (int r=0;r<4;r++){
                float sim = t1[r] - t2[r];
                Smat[(16*mt + 4*lg + r)*52 + 16*nt + lr] =
                    SCALE * sqrtf(sre[r]*sre[r] + sim*sim);
            }
        }
        __syncthreads();
        if (tid < 160){
            int row = tid>>2, part = tid&3, e0 = part*10;
            float mx = -1e30f;
            #pragma unroll
            for (int j=0;j<10;j++) mx = fmaxf(mx, Smat[row*52 + e0 + j]);
            mx = fmaxf(mx, __shfl_xor(mx,1));
            mx = fmaxf(mx, __shfl_xor(mx,2));
            float ex[10]; float sum=0.f;
            #pragma unroll
            for (int j=0;j<10;j++){ ex[j] = __expf(Smat[row*52+e0+j]-mx); sum += ex[j]; }
            sum += __shfl_xor(sum,1);
            sum += __shfl_xor(sum,2);
            float inv = 1.f/sum;
            #pragma unroll
            for (int j=0;j<10;j++) Smat[row*52+e0+j] = ex[j]*inv;
        }
        __syncthreads();
        for (int e=tid; e<3072; e+=256){
            int row = e>>6, col = e&63;
            float v = (row<40 && col<40)? Smat[row*52+col] : 0.f;
            P[row*88+col] = (__bf16)v;
        }
        {
            int t2 = tid & 127;
            __bf16* A = (tid<128)? Rt_r : Rt_i;
            int row = t2>>2, c4 = (t2&3)*4;
            *reinterpret_cast<bf16x4*>(A + row*88 + 48 + c4) = z4;
        }
        __syncthreads();
        for (int j=w; j<12; j+=4){
            int term = j/6, r2 = j - term*6;
            int dt = r2/3, nt = r2 - dt*3;
            const __bf16* Gv = term? Gv_i : Gv_r;
            f32x4 acc = zero4();
            #pragma unroll
            for (int ks=0; ks<2; ks++)
                acc = MFMA16(ldfrag(&Gv[(16*dt+lr)*88 + ks*32 + lg*8]),
                             ldfrag(&P [(16*nt+lr)*88 + ks*32 + lg*8]), acc);
            __bf16* dst = term? Rt_i : Rt_r;
            #pragma unroll
            for (int r=0;r<4;r++)
                dst[(16*dt + 4*lg + r)*88 + 16*nt + lr] = (__bf16)acc[r];
        }
        __syncthreads();
        for (int j=w; j<8; j+=4){
            int dt = j>>2, pt = j&3;
            f32x4 acc = zero4();
            #pragma unroll
            for (int ks=0; ks<2; ks++)
                acc = MFMA16(*reinterpret_cast<const bf16x8*>(nSi_g + (16*pt+lr)*64 + ks*32 + lg*8),
                             ldfrag(&Rt_i[(16*dt+lr)*88 + ks*32 + lg*8]), acc);
            #pragma unroll
            for (int ks=0; ks<2; ks++)
                acc = MFMA16(*reinterpret_cast<const bf16x8*>(Ci_g + (16*pt+lr)*64 + ks*32 + lg*8),
                             ldfrag(&Rt_r[(16*dt+lr)*88 + ks*32 + lg*8]), acc);
            #pragma unroll
            for (int r=0;r<4;r++){
                int p = 16*pt + 4*lg + r, d = 16*dt + lr;
                size_t idx = ((size_t)win*64 + p)*192 + h*32 + d;
                Fb[idx] = (__bf16)acc[r];
            }
        }
    } else {
        // =================== spatial path ===================
        float*  reltL = (float*) arena;                   // 5400 B
        __bf16* P     = (__bf16*)(arena + 5408);          // [64][72]
        __bf16* Vt    = (__bf16*)(arena + 14624);         // [32][72]
        int win = bid - 12288;
        int widx = win & 255;
        for (int e=tid; e<1350; e+=256) reltL[e] = relt[e];
        float mreg[16];
        int bidx[16];
        #pragma unroll
        for (int nt=0; nt<4; nt++)
            #pragma unroll
            for (int r=0;r<4;r++){
                int row = 16*w + 4*lg + r;
                int col = 16*nt + lr;
                mreg[nt*4+r] = mask[((widx*64 + row)<<6) + col];
                int dr = (row>>3)-(col>>3)+7, dc = (row&7)-(col&7)+7;
                bidx[nt*4+r] = (dr*15+dc)*6;
            }
        const size_t sbase = (size_t)win*64*576;
        const __bf16* Sq = S + sbase;
        const __bf16* Sk = S + sbase + 192;
        const __bf16* Sv = S + sbase + 384;
        for (int h=0; h<6; h++){
            __syncthreads();
            {
                int d = tid&31, pg = tid>>5;
                const __bf16* sp = Sv + (size_t)(pg*8)*576 + h*32 + d;
                bf16x4 v0, v1;
                v0[0]=sp[0];    v0[1]=sp[576];  v0[2]=sp[1152]; v0[3]=sp[1728];
                v1[0]=sp[2304]; v1[1]=sp[2880]; v1[2]=sp[3456]; v1[3]=sp[4032];
                *reinterpret_cast<bf16x4*>(&Vt[d*72 + pg*8])   = v0;
                *reinterpret_cast<bf16x4*>(&Vt[d*72 + pg*8+4]) = v1;
            }
            __syncthreads();
            bf16x8 aq = ldfrag(Sq + (size_t)(16*w+lr)*576 + h*32 + lg*8);
            f32x4 acc[4];
            #pragma unroll
            for (int nt=0;nt<4;nt++){
                bf16x8 bk = ldfrag(Sk + (size_t)(16*nt+lr)*576 + h*32 + lg*8);
                acc[nt] = MFMA16(aq, bk, zero4());
            }
            float p[16];
            #pragma unroll
            for (int r=0;r<4;r++){
                float sc[4];
                #pragma unroll
                for (int nt=0;nt<4;nt++)
                    sc[nt] = acc[nt][r]*SCALE + reltL[bidx[nt*4+r] + h] + mreg[nt*4+r];
                float mx = fmaxf(fmaxf(sc[0],sc[1]),fmaxf(sc[2],sc[3]));
                mx = fmaxf(mx, __shfl_xor(mx,1));
                mx = fmaxf(mx, __shfl_xor(mx,2));
                mx = fmaxf(mx, __shfl_xor(mx,4));
                mx = fmaxf(mx, __shfl_xor(mx,8));
                float sum = 0.f;
                #pragma unroll
                for (int nt=0;nt<4;nt++){ sc[nt] = __expf(sc[nt]-mx); sum += sc[nt]; }
                sum += __shfl_xor(sum,1);
                sum += __shfl_xor(sum,2);
                sum += __shfl_xor(sum,4);
                sum += __shfl_xor(sum,8);
                float inv = 1.f/sum;
                #pragma unroll
                for (int nt=0;nt<4;nt++) p[r*4+nt] = sc[nt]*inv;
            }
            #pragma unroll
            for (int r=0;r<4;r++)
                #pragma unroll
                for (int nt=0;nt<4;nt++)
                    P[(16*w + 4*lg + r)*72 + 16*nt + lr] = (__bf16)p[r*4+nt];
            #pragma unroll
            for (int dt=0; dt<2; dt++){
                f32x4 o = zero4();
                #pragma unroll
                for (int ks=0; ks<2; ks++)
                    o = MFMA16(ldfrag(&P[(16*w+lr)*72 + ks*32 + lg*8]),
                               ldfrag(&Vt[(16*dt+lr)*72 + ks*32 + lg*8]), o);
                #pragma unroll
                for (int r=0;r<4;r++){
                    int row = 16*w + 4*lg + r;
                    Bb[((size_t)win*64 + row)*192 + h*32 + 16*dt + lr] = (__bf16)o[r];
                }
            }
        }
    }
}

// ------- K3: fused FFN: proj(Bb+Fb) + residual + LN2 + fc1 + GELU + fc2 + res
__global__ __launch_bounds__(256,3) void k_ffn(const __bf16* __restrict__ Bb,
        const __bf16* __restrict__ Fb,
        const float* __restrict__ x, const __bf16* __restrict__ Wpt,
        const float* __restrict__ proj_b, const float* __restrict__ g2,
        const float* __restrict__ b2v, const __bf16* __restrict__ W1t,
        const float* __restrict__ fc1b, const __bf16* __restrict__ W2t,
        const float* __restrict__ fc2b, float* __restrict__ out){
    __shared__ __align__(16) __bf16 hb[64*200];   // hbuf
    __shared__ __align__(16) __bf16 yb[64*200];   // y bf16 -> xln (in-place)
    int tid = threadIdx.x;
    int win = blockIdx.x;
    int lane = tid&63, w = tid>>6, lr = lane&15, lg = lane>>4;
    int bb = win>>8, rem = win&255, wh = rem>>4, wwi = rem&15;
    // ---- proj MFMA, A = bf16(Bb + Fb) direct from global
    const __bf16* Ab = Bb + (size_t)win*64*192;
    const __bf16* Af = Fb + (size_t)win*64*192;
    f32x4 acc[4][3];
    #pragma unroll
    for (int m=0;m<4;m++)
        #pragma unroll
        for (int n=0;n<3;n++) acc[m][n] = zero4();
    #pragma unroll
    for (int kc=0; kc<6; kc++){
        int ko = kc*32 + lg*8;
        bf16x8 a[4];
        #pragma unroll
        for (int m=0;m<4;m++){
            bf16x8 ab = ldfrag(Ab + (size_t)(16*m+lr)*192 + ko);
            bf16x8 fb = ldfrag(Af + (size_t)(16*m+lr)*192 + ko);
            bf16x8 s;
            #pragma unroll
            for (int j=0;j<8;j++) s[j] = (__bf16)((float)ab[j] + (float)fb[j]);
            a[m] = s;
        }
        bf16x8 bfr[3];
        #pragma unroll
        for (int n=0;n<3;n++)
            bfr[n] = ldfrag(Wpt + (size_t)(48*w + 16*n + lr)*192 + ko);
        #pragma unroll
        for (int m=0;m<4;m++)
            #pragma unroll
            for (int n=0;n<3;n++) acc[m][n] = MFMA16(a[m], bfr[n], acc[m][n]);
    }
    // ---- y = proj + bias + x (residual); bf16 copy in regs + LDS tile
    bf16x4 yreg[4][3];
    #pragma unroll
    for (int m=0;m<4;m++)
        #pragma unroll
        for (int r=0;r<4;r++){
            int t = 16*m + 4*lg + r;
            int p = wh*8 + (t>>3), q = wwi*8 + (t&7);
            int hh = (p+SSH)&127, w2 = (q+SSH)&127;
            size_t pixb = (((size_t)bb*128 + hh)*128 + w2)*192;
            #pragma unroll
            for (int n=0;n<3;n++){
                int col = 48*w + 16*n + lr;
                float yv = acc[m][n][r] + proj_b[col] + x[pixb + col];
                __bf16 yh = (__bf16)yv;
                yreg[m][n][r] = yh;
                yb[t*200 + col] = yh;
            }
        }
    __syncthreads();
    // ---- LN2 in-place on yb
    {
        int tok = tid>>2, part = tid&3;
        float v[48];
        #pragma unroll
        for (int i8=0;i8<6;i8++){
            bf16x8 pk = *reinterpret_cast<const bf16x8*>(&yb[tok*200 + part*48 + i8*8]);
            #pragma unroll
            for (int j=0;j<8;j++) v[i8*8+j] = (float)pk[j];
        }
        float s=0.f, ss=0.f;
        #pragma unroll
        for (int i=0;i<48;i++){ s+=v[i]; ss+=v[i]*v[i]; }
        s  += __shfl_xor(s,1);  s  += __shfl_xor(s,2);
        ss += __shfl_xor(ss,1); ss += __shfl_xor(ss,2);
        float mean = s*(1.f/192.f);
        float rstd = rsqrtf(ss*(1.f/192.f) - mean*mean + 1e-5f);
        #pragma unroll
        for (int i8=0;i8<6;i8++){
            bf16x8 pk;
            #pragma unroll
            for (int j=0;j<8;j++){
                int ch = part*48 + i8*8 + j;
                pk[j] = (__bf16)((v[i8*8+j]-mean)*rstd*g2[ch] + b2v[ch]);
            }
            *reinterpret_cast<bf16x8*>(&yb[tok*200 + part*48 + i8*8]) = pk;
        }
    }
    __syncthreads();
    // ---- MLP
    f32x4 acc2[4][3];
    #pragma unroll
    for (int m=0;m<4;m++)
        #pragma unroll
        for (int n=0;n<3;n++) acc2[m][n] = zero4();
    for (int hc=0; hc<4; hc++){
        f32x4 acc1[4][3];
        #pragma unroll
        for (int m=0;m<4;m++)
            #pragma unroll
            for (int n=0;n<3;n++) acc1[m][n] = zero4();
        #pragma unroll
        for (int kc=0; kc<6; kc++){
            int ko = kc*32 + lg*8;
            bf16x8 a[4];
            #pragma unroll
            for (int m=0;m<4;m++) a[m] = ldfrag(&yb[(16*m+lr)*200 + ko]);
            bf16x8 bfr[3];
            #pragma unroll
            for (int n=0;n<3;n++)
                bfr[n] = ldfrag(W1t + (size_t)(hc*192 + 48*w + 16*n + lr)*192 + ko);
            #pragma unroll
            for (int m=0;m<4;m++)
                #pragma unroll
                for (int n=0;n<3;n++) acc1[m][n] = MFMA16(a[m], bfr[n], acc1[m][n]);
        }
        #pragma unroll
        for (int n=0;n<3;n++){
            int jcol = 48*w + 16*n + lr;
            float b1 = fc1b[hc*192 + jcol];
            #pragma unroll
            for (int m=0;m<4;m++)
                #pragma unroll
                for (int r=0;r<4;r++){
                    float xv = acc1[m][n][r] + b1;
                    hb[(16*m + 4*lg + r)*200 + jcol] = (__bf16)gelu_fast(xv);
                }
        }
        __syncthreads();
        #pragma unroll
        for (int kc=0; kc<6; kc++){
            int ko = kc*32 + lg*8;
            bf16x8 a[4];
            #pragma unroll
            for (int m=0;m<4;m++) a[m] = ldfrag(&hb[(16*m+lr)*200 + ko]);
            bf16x8 bfr[3];
            #pragma unroll
            for (int n=0;n<3;n++)
                bfr[n] = ldfrag(W2t + (size_t)(48*w + 16*n + lr)*768 + hc*192 + ko);
            #pragma unroll
            for (int m=0;m<4;m++)
                #pragma unroll
                for (int n=0;n<3;n++) acc2[m][n] = MFMA16(a[m], bfr[n], acc2[m][n]);
        }
        __syncthreads();
    }
    // ---- final: out = acc2 + fc2b + y (scattered pixel write)
    #pragma unroll
    for (int m=0;m<4;m++)
        #pragma unroll
        for (int r=0;r<4;r++){
            int t = 16*m + 4*lg + r;
            int p = wh*8 + (t>>3), q = wwi*8 + (t&7);
            int hh = (p+SSH)&127, w2 = (q+SSH)&127;
            size_t pixb = (((size_t)bb*128 + hh)*128 + w2)*192;
            #pragma unroll
            for (int n=0;n<3;n++){
                int col = 48*w + 16*n + lr;
                out[pixb + col] = acc2[m][n][r] + fc2b[col] + (float)yreg[m][n][r];
            }
        }
}

extern "C" void kernel_launch(void* const* d_in, const int* in_sizes, int n_in,
                              void* d_out, int out_size, void* d_ws, size_t ws_size,
                              hipStream_t stream) {
    const float* x     = (const float*)d_in[0];
    const float* mask  = (const float*)d_in[1];
    const float* n1g   = (const float*)d_in[2];
    const float* n1b   = (const float*)d_in[3];
    const float* qkvw  = (const float*)d_in[4];
    const float* qkvb  = (const float*)d_in[5];
    const float* relt  = (const float*)d_in[6];
    const float* projw = (const float*)d_in[7];
    const float* projb = (const float*)d_in[8];
    const float* n2g   = (const float*)d_in[9];
    const float* n2b   = (const float*)d_in[10];
    const float* fc1w  = (const float*)d_in[11];
    const float* fc1b  = (const float*)d_in[12];
    const float* fc2w  = (const float*)d_in[13];
    const float* fc2b  = (const float*)d_in[14];
    float* out = (float*)d_out;

    char* wsb = (char*)d_ws;
    __bf16* Sb  = (__bf16*)wsb;                        // 150,994,944 B
    __bf16* Bb  = (__bf16*)(wsb + 150994944);          //  50,331,648 B (spatial out)
    __bf16* Fb  = (__bf16*)(wsb + 201326592);          //  50,331,648 B (fourier out)
    __bf16* Wqt = (__bf16*)(wsb + 251658240);          //    221,184 B
    __bf16* Wpt = (__bf16*)(wsb + 251879424);          //     73,728 B
    __bf16* W1t = (__bf16*)(wsb + 251953152);          //    294,912 B
    __bf16* W2t = (__bf16*)(wsb + 252248064);          //    294,912 B
    __bf16* Fre = (__bf16*)(wsb + 252542976);          //      6,144 B
    __bf16* Fim = (__bf16*)(wsb + 252549120);          //      6,144 B
    __bf16* Ci  = (__bf16*)(wsb + 252555264);          //      8,192 B
    __bf16* nSi = (__bf16*)(wsb + 252563456);          //      8,192 B

    k_prep  <<<576,   256, 0, stream>>>(qkvw, projw, fc1w, fc2w, Wqt, Wpt, W1t, W2t,
                                        Fre, Fim, Ci, nSi);
    k_qkv   <<<2048,  256, 0, stream>>>(x, n1g, n1b, Wqt, qkvb, Sb);
    k_attn2 <<<14336, 256, 0, stream>>>(Sb, relt, mask, qkvb, Fre, Fim, Ci, nSi, Bb, Fb);
    k_ffn   <<<2048,  256, 0, stream>>>(Bb, Fb, x, Wpt, projb, n2g, n2b,
                                        W1t, fc1b, W2t, fc2b, out);
}

// Round 19
// 595.850 us; speedup vs baseline: 1.0720x; 1.0720x over previous
//
#include <hip/hip_runtime.h>
#include <hip/hip_bf16.h>
#include <math.h>

#define SSH 4
#define SCALE 0.17677669529663687f  // 1/sqrt(32)

typedef __bf16 bf16x8 __attribute__((ext_vector_type(8)));
typedef __bf16 bf16x4 __attribute__((ext_vector_type(4)));
typedef unsigned short ushort8 __attribute__((ext_vector_type(8)));
typedef float  f32x4  __attribute__((ext_vector_type(4)));

static __device__ __forceinline__ f32x4 mfma16(bf16x8 a, bf16x8 b, f32x4 c){
    return __builtin_amdgcn_mfma_f32_16x16x32_bf16(a, b, c, 0, 0, 0);
}
#define MFMA16(a,b,c) mfma16((a),(b),(c))

static __device__ __forceinline__ bf16x8 ldfrag(const __bf16* p){
    return *reinterpret_cast<const bf16x8*>(p);
}
static __device__ __forceinline__ f32x4 zero4(){
    f32x4 z; z[0]=0.f; z[1]=0.f; z[2]=0.f; z[3]=0.f; return z;
}
// tanh-form GELU via sigmoid identity: 0.5x(1+tanh(u)) == x * sigma(2u)
static __device__ __forceinline__ float gelu_fast(float x){
    float u = x*(0.7978845608f + 0.0356774081f*x*x);
    return __fdividef(x, 1.f + __expf(-2.f*u));
}

// ---------------- K0: weight prep (bf16 [N][K]) + Fourier constant tables ----
__global__ __launch_bounds__(256) void k_prep(const float* __restrict__ qkvw,
        const float* __restrict__ projw, const float* __restrict__ fc1w,
        const float* __restrict__ fc2w, __bf16* __restrict__ Wq,
        __bf16* __restrict__ Wp, __bf16* __restrict__ W1, __bf16* __restrict__ W2,
        __bf16* __restrict__ Fre, __bf16* __restrict__ Fim,
        __bf16* __restrict__ Ci,  __bf16* __restrict__ nSi){
    int i = blockIdx.x*256 + threadIdx.x;
    if (i < 110592){ int n = i/192, k = i - n*192; Wq[i] = (__bf16)qkvw[k*576 + n]; }
    if (i < 36864) { int n = i/192, k = i - n*192; Wp[i] = (__bf16)projw[k*192 + n]; }
    if (i < 147456){ int n = i/192, k = i - n*192; W1[i] = (__bf16)fc1w[k*768 + n]; }
    if (i < 147456){ int n = i/768, k = i - n*768; W2[i] = (__bf16)fc2w[k*192 + n]; }
    if (i < 3072){
        int n = i>>6, p = i&63;
        float vr = 0.f, vi = 0.f;
        if (n < 40){
            int u = n/5, v = n - u*5, r = p>>3, c = p&7;
            int k = (u*r + v*c)&7;
            float ang = (float)k * 0.78539816339744831f;
            vr = cosf(ang)*0.125f; vi = -sinf(ang)*0.125f;
        }
        Fre[i] = (__bf16)vr; Fim[i] = (__bf16)vi;
    }
    if (i < 4096){
        int p = i>>6, n = i&63;
        float vc = 0.f, vs = 0.f;
        if (n < 40){
            int u = n/5, v = n - u*5, r = p>>3, c = p&7;
            int k = (u*r + v*c)&7;
            float ang = (float)k * 0.78539816339744831f;
            float wv = (v>=1 && v<=3)? 2.f : 1.f;
            vc = wv*cosf(ang)*0.125f; vs = -wv*sinf(ang)*0.125f;
        }
        Ci[i] = (__bf16)vc; nSi[i] = (__bf16)vs;
    }
}

// ---------------- K1: LN1 + shift + qkv GEMM (MFMA, staged W + coalesced S) --
__global__ __launch_bounds__(256,2) void k_qkv(const float* __restrict__ x,
        const float* __restrict__ n1g, const float* __restrict__ n1b,
        const __bf16* __restrict__ Wqt, const float* __restrict__ qkv_b,
        __bf16* __restrict__ S){
    __shared__ __align__(16) __bf16 xw[64*200];
    __shared__ __align__(16) __bf16 Wt[192*72];
    __shared__ __align__(16) __bf16 Ss[64*200];
    int tid = threadIdx.x;
    int win = blockIdx.x;
    int bb = win>>8, rem = win&255, wh = rem>>4, wwi = rem&15;
    {
        int tok = tid>>2, part = tid&3;
        int r = tok>>3, c = tok&7;
        int sh = (wh*8 + r + SSH)&127, sw = (wwi*8 + c + SSH)&127;
        const float* srcp = x + (((size_t)(bb*128+sh))*128 + sw)*192 + part*48;
        float v[48];
        #pragma unroll
        for (int i=0;i<12;i++){
            float4 t4 = *reinterpret_cast<const float4*>(srcp + i*4);
            v[i*4]=t4.x; v[i*4+1]=t4.y; v[i*4+2]=t4.z; v[i*4+3]=t4.w;
        }
        float s=0.f, ss=0.f;
        #pragma unroll
        for (int i=0;i<48;i++){ s+=v[i]; ss+=v[i]*v[i]; }
        s  += __shfl_xor(s,1);  s  += __shfl_xor(s,2);
        ss += __shfl_xor(ss,1); ss += __shfl_xor(ss,2);
        float mean = s*(1.f/192.f);
        float rstd = rsqrtf(ss*(1.f/192.f) - mean*mean + 1e-5f);
        #pragma unroll
        for (int i8=0;i8<6;i8++){
            bf16x8 pk;
            #pragma unroll
            for (int j=0;j<8;j++){
                int ch = part*48 + i8*8 + j;
                pk[j] = (__bf16)((v[i8*8+j]-mean)*rstd*n1g[ch] + n1b[ch]);
            }
            *reinterpret_cast<bf16x8*>(&xw[tok*200 + part*48 + i8*8]) = pk;
        }
    }
    int lane = tid&63, w = tid>>6, lr = lane&15, lg = lane>>4;
    ushort8 wreg[6];
    auto ldW = [&](int s, ushort8* wr){
        int nc = s/3, kc = s - nc*3;
        #pragma unroll
        for (int i=0;i<6;i++){
            int e = tid + i*256;
            int j = e>>3, k8 = e&7;
            wr[i] = *reinterpret_cast<const ushort8*>(
                reinterpret_cast<const unsigned short*>(Wqt) + (size_t)(nc*192+j)*192 + kc*64 + k8*8);
        }
    };
    auto stW = [&](ushort8* wr){
        #pragma unroll
        for (int i=0;i<6;i++){
            int e = tid + i*256;
            int j = e>>3, k8 = e&7;
            *reinterpret_cast<ushort8*>(reinterpret_cast<unsigned short*>(Wt) + j*72 + k8*8) = wr[i];
        }
    };
    ldW(0, wreg);
    __syncthreads();
    stW(wreg);
    __syncthreads();
    f32x4 acc[4][3];
    #pragma unroll
    for (int m=0;m<4;m++)
        #pragma unroll
        for (int n=0;n<3;n++) acc[m][n] = zero4();
    for (int s=0; s<9; s++){
        int nc = s/3, kc = s - nc*3;
        if (s<8) ldW(s+1, wreg);
        #pragma unroll
        for (int kk=0; kk<2; kk++){
            int ko = kc*64 + kk*32 + lg*8;
            bf16x8 a[4];
            #pragma unroll
            for (int m=0;m<4;m++) a[m] = ldfrag(&xw[(16*m+lr)*200 + ko]);
            int klo = kk*32 + lg*8;
            bf16x8 bfr[3];
            #pragma unroll
            for (int n=0;n<3;n++) bfr[n] = ldfrag(&Wt[(48*w+16*n+lr)*72 + klo]);
            #pragma unroll
            for (int m=0;m<4;m++)
                #pragma unroll
                for (int n=0;n<3;n++) acc[m][n] = MFMA16(a[m], bfr[n], acc[m][n]);
        }
        if (kc==2){
            #pragma unroll
            for (int n=0;n<3;n++){
                int colL = 48*w + 16*n + lr;
                float bias = qkv_b[nc*192 + colL];
                #pragma unroll
                for (int m=0;m<4;m++)
                    #pragma unroll
                    for (int r=0;r<4;r++){
                        Ss[(16*m + 4*lg + r)*200 + colL] = (__bf16)(acc[m][n][r] + bias);
                        acc[m][n][r] = 0.f;
                    }
            }
        }
        __syncthreads();
        if (kc==2){
            #pragma unroll
            for (int i=0;i<6;i++){
                int e = tid + i*256;
                int row = e/24, c8 = e - row*24;
                *reinterpret_cast<bf16x8*>(S + (size_t)(win*64+row)*576 + nc*192 + c8*8) =
                    *reinterpret_cast<const bf16x8*>(&Ss[row*200 + c8*8]);
            }
        }
        if (s<8) stW(wreg);
        __syncthreads();
    }
}

// ------- K2: heterogeneous attention launch: blocks [0,12288) = fourier->Fb,
//         blocks [12288,14336) = spatial->Bb. Independent, run concurrently. --
__global__ __launch_bounds__(256,3) void k_attn2(const __bf16* __restrict__ S,
        const float* __restrict__ relt, const float* __restrict__ mask,
        const float* __restrict__ qkv_b,
        const __bf16* __restrict__ Fre_g, const __bf16* __restrict__ Fim_g,
        const __bf16* __restrict__ Ci_g,  const __bf16* __restrict__ nSi_g,
        __bf16* __restrict__ Bb, __bf16* __restrict__ Fb){
    __shared__ __align__(16) unsigned char arena[51968];
    int tid = threadIdx.x;
    int bid = blockIdx.x;
    int lane = tid&63, w = tid>>6, lr = lane&15, lg = lane>>4;
    bf16x4 z4; z4[0]=z4[1]=z4[2]=z4[3]=(__bf16)0.f;
    if (bid < 12288){
        // =================== fourier path ===================
        __bf16* Gq_r = (__bf16*)(arena);             // [48][40]
        __bf16* Gqin = (__bf16*)(arena + 3840);
        __bf16* Gk_r = (__bf16*)(arena + 7680);
        __bf16* Gk_i = (__bf16*)(arena + 11520);
        __bf16* Rt_r = (__bf16*)(arena);             // [32][88] overlay
        __bf16* Rt_i = (__bf16*)(arena + 5632);
        __bf16* Gv_r = (__bf16*)(arena + 15360);
        __bf16* Gv_i = (__bf16*)(arena + 20992);
        __bf16* St3  = (__bf16*)(arena + 26624);     // [3][32][88]
        float*  Smat = (float*) (arena + 26624);     // [48][52] overlay
        __bf16* P    = (__bf16*)(arena + 43520);     // [48][88]
        int win = bid / 6, h = bid - win*6;
        const size_t sbase = (size_t)win*64*576 + h*32;
        {
            int t2 = tid & 127;
            __bf16* A = (tid<128)? Gv_r : Gv_i;
            int row = t2>>2, c4 = (t2&3)*4;
            *reinterpret_cast<bf16x4*>(A + row*88 + 48 + c4) = z4;
        }
        {
            int d = tid&31, pg = tid>>5;
            #pragma unroll
            for (int m=0;m<3;m++){
                const __bf16* sp = S + sbase + (size_t)m*192 + (size_t)pg*8*576 + d;
                bf16x4 v0, v1;
                v0[0]=sp[0];      v0[1]=sp[576];    v0[2]=sp[1152];   v0[3]=sp[1728];
                v1[0]=sp[2304];   v1[1]=sp[2880];   v1[2]=sp[3456];   v1[3]=sp[4032];
                *reinterpret_cast<bf16x4*>(&St3[m*2816 + d*88 + pg*8])     = v0;
                *reinterpret_cast<bf16x4*>(&St3[m*2816 + d*88 + pg*8 + 4]) = v1;
            }
        }
        __syncthreads();
        for (int j=w; j<36; j+=4){
            int m = j/12, jj = j - m*12;
            int term = jj/6, r2 = jj - term*6;
            const __bf16* Stm = &St3[m*2816];
            if (m<2){
                int mt = r2>>1, nt = r2&1;
                const __bf16* Ag = (term? Fim_g : Fre_g) + (16*mt+lr)*64 + lg*8;
                f32x4 acc = zero4();
                acc = MFMA16(*reinterpret_cast<const bf16x8*>(Ag),
                             ldfrag(&Stm[(16*nt+lr)*88 + lg*8]), acc);
                acc = MFMA16(*reinterpret_cast<const bf16x8*>(Ag+32),
                             ldfrag(&Stm[(16*nt+lr)*88 + 32 + lg*8]), acc);
                int d = 16*nt + lr;
                float b = qkv_b[m*192 + h*32 + d];
                __bf16* dst = (m==0)? (term? Gqin : Gq_r) : (term? Gk_i : Gk_r);
                #pragma unroll
                for (int r=0;r<4;r++){
                    int n = 16*mt + 4*lg + r;
                    float val = acc[r] + ((term==0) ? ((n==0)? -7.f*b : b) : b);
                    if (m==0 && term==1) val = -val;     // store -Qi
                    dst[n*40 + d] = (__bf16)val;
                }
            } else {
                int mt = r2/3, nt = r2 - mt*3;
                const __bf16* Bg = (term? Fim_g : Fre_g) + (16*nt+lr)*64 + lg*8;
                f32x4 acc = zero4();
                acc = MFMA16(ldfrag(&Stm[(16*mt+lr)*88 + lg*8]),
                             *reinterpret_cast<const bf16x8*>(Bg), acc);
                acc = MFMA16(ldfrag(&Stm[(16*mt+lr)*88 + 32 + lg*8]),
                             *reinterpret_cast<const bf16x8*>(Bg+32), acc);
                int n = 16*nt + lr;
                __bf16* dst = term? Gv_i : Gv_r;
                #pragma unroll
                for (int r=0;r<4;r++){
                    int d = 16*mt + 4*lg + r;
                    float b = qkv_b[2*192 + h*32 + d];
                    float val = acc[r] + ((term==0) ? ((n==0)? -7.f*b : b) : b);
                    dst[d*88 + n] = (__bf16)val;
                }
            }
        }
        __syncthreads();
        for (int j=w; j<9; j+=4){
            int mt = j/3, nt = j - mt*3;
            bf16x8 qr = ldfrag(&Gq_r[(16*mt+lr)*40 + lg*8]);
            bf16x8 qi = ldfrag(&Gqin[(16*mt+lr)*40 + lg*8]);
            bf16x8 kr = ldfrag(&Gk_r[(16*nt+lr)*40 + lg*8]);
            bf16x8 ki = ldfrag(&Gk_i[(16*nt+lr)*40 + lg*8]);
            f32x4 sre = MFMA16(qi, ki, zero4());   // (-Qi).Ki
            sre = MFMA16(qr, kr, sre);             // + Qr.Kr
            f32x4 t1 = MFMA16(qr, ki, zero4());    // Qr.Ki
            f32x4 t2 = MFMA16(qi, kr, zero4());    // (-Qi).Kr
            #pragma unroll
            for (int r=0;r<4;r++){
                float sim = t1[r] - t2[r];
                Smat[(16*mt + 4*lg + r)*52 + 16*nt + lr] =
                    SCALE * sqrtf(sre[r]*sre[r] + sim*sim);
            }
        }
        __syncthreads();
        if (tid < 160){
            int row = tid>>2, part = tid&3, e0 = part*10;
            float mx = -1e30f;
            #pragma unroll
            for (int j=0;j<10;j++) mx = fmaxf(mx, Smat[row*52 + e0 + j]);
            mx = fmaxf(mx, __shfl_xor(mx,1));
            mx = fmaxf(mx, __shfl_xor(mx,2));
            float ex[10]; float sum=0.f;
            #pragma unroll
            for (int j=0;j<10;j++){ ex[j] = __expf(Smat[row*52+e0+j]-mx); sum += ex[j]; }
            sum += __shfl_xor(sum,1);
            sum += __shfl_xor(sum,2);
            float inv = 1.f/sum;
            #pragma unroll
            for (int j=0;j<10;j++) Smat[row*52+e0+j] = ex[j]*inv;
        }
        __syncthreads();
        for (int e=tid; e<3072; e+=256){
            int row = e>>6, col = e&63;
            float v = (row<40 && col<40)? Smat[row*52+col] : 0.f;
            P[row*88+col] = (__bf16)v;
        }
        {
            int t2 = tid & 127;
            __bf16* A = (tid<128)? Rt_r : Rt_i;
            int row = t2>>2, c4 = (t2&3)*4;
            *reinterpret_cast<bf16x4*>(A + row*88 + 48 + c4) = z4;
        }
        __syncthreads();
        for (int j=w; j<12; j+=4){
            int term = j/6, r2 = j - term*6;
            int dt = r2/3, nt = r2 - dt*3;
            const __bf16* Gv = term? Gv_i : Gv_r;
            f32x4 acc = zero4();
            #pragma unroll
            for (int ks=0; ks<2; ks++)
                acc = MFMA16(ldfrag(&Gv[(16*dt+lr)*88 + ks*32 + lg*8]),
                             ldfrag(&P [(16*nt+lr)*88 + ks*32 + lg*8]), acc);
            __bf16* dst = term? Rt_i : Rt_r;
            #pragma unroll
            for (int r=0;r<4;r++)
                dst[(16*dt + 4*lg + r)*88 + 16*nt + lr] = (__bf16)acc[r];
        }
        __syncthreads();
        for (int j=w; j<8; j+=4){
            int dt = j>>2, pt = j&3;
            f32x4 acc = zero4();
            #pragma unroll
            for (int ks=0; ks<2; ks++)
                acc = MFMA16(*reinterpret_cast<const bf16x8*>(nSi_g + (16*pt+lr)*64 + ks*32 + lg*8),
                             ldfrag(&Rt_i[(16*dt+lr)*88 + ks*32 + lg*8]), acc);
            #pragma unroll
            for (int ks=0; ks<2; ks++)
                acc = MFMA16(*reinterpret_cast<const bf16x8*>(Ci_g + (16*pt+lr)*64 + ks*32 + lg*8),
                             ldfrag(&Rt_r[(16*dt+lr)*88 + ks*32 + lg*8]), acc);
            #pragma unroll
            for (int r=0;r<4;r++){
                int p = 16*pt + 4*lg + r, d = 16*dt + lr;
                size_t idx = ((size_t)win*64 + p)*192 + h*32 + d;
                Fb[idx] = (__bf16)acc[r];
            }
        }
    } else {
        // =================== spatial path ===================
        float*  reltL = (float*) arena;                   // 5400 B
        __bf16* P     = (__bf16*)(arena + 5408);          // [64][72]
        __bf16* Vt    = (__bf16*)(arena + 14624);         // [32][72]
        int win = bid - 12288;
        int widx = win & 255;
        for (int e=tid; e<1350; e+=256) reltL[e] = relt[e];
        float mreg[16];
        int bidx[16];
        #pragma unroll
        for (int nt=0; nt<4; nt++)
            #pragma unroll
            for (int r=0;r<4;r++){
                int row = 16*w + 4*lg + r;
                int col = 16*nt + lr;
                mreg[nt*4+r] = mask[((widx*64 + row)<<6) + col];
                int dr = (row>>3)-(col>>3)+7, dc = (row&7)-(col&7)+7;
                bidx[nt*4+r] = (dr*15+dc)*6;
            }
        const size_t sbase = (size_t)win*64*576;
        const __bf16* Sq = S + sbase;
        const __bf16* Sk = S + sbase + 192;
        const __bf16* Sv = S + sbase + 384;
        for (int h=0; h<6; h++){
            __syncthreads();
            {
                int d = tid&31, pg = tid>>5;
                const __bf16* sp = Sv + (size_t)(pg*8)*576 + h*32 + d;
                bf16x4 v0, v1;
                v0[0]=sp[0];    v0[1]=sp[576];  v0[2]=sp[1152]; v0[3]=sp[1728];
                v1[0]=sp[2304]; v1[1]=sp[2880]; v1[2]=sp[3456]; v1[3]=sp[4032];
                *reinterpret_cast<bf16x4*>(&Vt[d*72 + pg*8])   = v0;
                *reinterpret_cast<bf16x4*>(&Vt[d*72 + pg*8+4]) = v1;
            }
            __syncthreads();
            bf16x8 aq = ldfrag(Sq + (size_t)(16*w+lr)*576 + h*32 + lg*8);
            f32x4 acc[4];
            #pragma unroll
            for (int nt=0;nt<4;nt++){
                bf16x8 bk = ldfrag(Sk + (size_t)(16*nt+lr)*576 + h*32 + lg*8);
                acc[nt] = MFMA16(aq, bk, zero4());
            }
            float p[16];
            #pragma unroll
            for (int r=0;r<4;r++){
                float sc[4];
                #pragma unroll
                for (int nt=0;nt<4;nt++)
                    sc[nt] = acc[nt][r]*SCALE + reltL[bidx[nt*4+r] + h] + mreg[nt*4+r];
                float mx = fmaxf(fmaxf(sc[0],sc[1]),fmaxf(sc[2],sc[3]));
                mx = fmaxf(mx, __shfl_xor(mx,1));
                mx = fmaxf(mx, __shfl_xor(mx,2));
                mx = fmaxf(mx, __shfl_xor(mx,4));
                mx = fmaxf(mx, __shfl_xor(mx,8));
                float sum = 0.f;
                #pragma unroll
                for (int nt=0;nt<4;nt++){ sc[nt] = __expf(sc[nt]-mx); sum += sc[nt]; }
                sum += __shfl_xor(sum,1);
                sum += __shfl_xor(sum,2);
                sum += __shfl_xor(sum,4);
                sum += __shfl_xor(sum,8);
                float inv = 1.f/sum;
                #pragma unroll
                for (int nt=0;nt<4;nt++) p[r*4+nt] = sc[nt]*inv;
            }
            #pragma unroll
            for (int r=0;r<4;r++)
                #pragma unroll
                for (int nt=0;nt<4;nt++)
                    P[(16*w + 4*lg + r)*72 + 16*nt + lr] = (__bf16)p[r*4+nt];
            #pragma unroll
            for (int dt=0; dt<2; dt++){
                f32x4 o = zero4();
                #pragma unroll
                for (int ks=0; ks<2; ks++)
                    o = MFMA16(ldfrag(&P[(16*w+lr)*72 + ks*32 + lg*8]),
                               ldfrag(&Vt[(16*dt+lr)*72 + ks*32 + lg*8]), o);
                #pragma unroll
                for (int r=0;r<4;r++){
                    int row = 16*w + 4*lg + r;
                    Bb[((size_t)win*64 + row)*192 + h*32 + 16*dt + lr] = (__bf16)o[r];
                }
            }
        }
    }
}

// ------- K3: fused FFN: proj(Bb+Fb) + residual + LN2 + fc1 + GELU + fc2 + res
__global__ __launch_bounds__(256,2) void k_ffn(const __bf16* __restrict__ Bb,
        const __bf16* __restrict__ Fb,
        const float* __restrict__ x, const __bf16* __restrict__ Wpt,
        const float* __restrict__ proj_b, const float* __restrict__ g2,
        const float* __restrict__ b2v, const __bf16* __restrict__ W1t,
        const float* __restrict__ fc1b, const __bf16* __restrict__ W2t,
        const float* __restrict__ fc2b, float* __restrict__ out){
    __shared__ __align__(16) __bf16 hb[64*200];   // hbuf
    __shared__ __align__(16) __bf16 yb[64*200];   // y bf16 -> xln (in-place)
    int tid = threadIdx.x;
    int win = blockIdx.x;
    int lane = tid&63, w = tid>>6, lr = lane&15, lg = lane>>4;
    int bb = win>>8, rem = win&255, wh = rem>>4, wwi = rem&15;
    // ---- proj MFMA, A = bf16(Bb + Fb) direct from global
    const __bf16* Ab = Bb + (size_t)win*64*192;
    const __bf16* Af = Fb + (size_t)win*64*192;
    f32x4 acc[4][3];
    #pragma unroll
    for (int m=0;m<4;m++)
        #pragma unroll
        for (int n=0;n<3;n++) acc[m][n] = zero4();
    #pragma unroll
    for (int kc=0; kc<6; kc++){
        int ko = kc*32 + lg*8;
        bf16x8 a[4];
        #pragma unroll
        for (int m=0;m<4;m++){
            bf16x8 ab = ldfrag(Ab + (size_t)(16*m+lr)*192 + ko);
            bf16x8 fb = ldfrag(Af + (size_t)(16*m+lr)*192 + ko);
            bf16x8 s;
            #pragma unroll
            for (int j=0;j<8;j++) s[j] = (__bf16)((float)ab[j] + (float)fb[j]);
            a[m] = s;
        }
        bf16x8 bfr[3];
        #pragma unroll
        for (int n=0;n<3;n++)
            bfr[n] = ldfrag(Wpt + (size_t)(48*w + 16*n + lr)*192 + ko);
        #pragma unroll
        for (int m=0;m<4;m++)
            #pragma unroll
            for (int n=0;n<3;n++) acc[m][n] = MFMA16(a[m], bfr[n], acc[m][n]);
    }
    // ---- y = proj + bias + x (residual); bf16 copy in regs + LDS tile
    bf16x4 yreg[4][3];
    #pragma unroll
    for (int m=0;m<4;m++)
        #pragma unroll
        for (int r=0;r<4;r++){
            int t = 16*m + 4*lg + r;
            int p = wh*8 + (t>>3), q = wwi*8 + (t&7);
            int hh = (p+SSH)&127, w2 = (q+SSH)&127;
            size_t pixb = (((size_t)bb*128 + hh)*128 + w2)*192;
            #pragma unroll
            for (int n=0;n<3;n++){
                int col = 48*w + 16*n + lr;
                float yv = acc[m][n][r] + proj_b[col] + x[pixb + col];
                __bf16 yh = (__bf16)yv;
                yreg[m][n][r] = yh;
                yb[t*200 + col] = yh;
            }
        }
    __syncthreads();
    // ---- LN2 in-place on yb
    {
        int tok = tid>>2, part = tid&3;
        float v[48];
        #pragma unroll
        for (int i8=0;i8<6;i8++){
            bf16x8 pk = *reinterpret_cast<const bf16x8*>(&yb[tok*200 + part*48 + i8*8]);
            #pragma unroll
            for (int j=0;j<8;j++) v[i8*8+j] = (float)pk[j];
        }
        float s=0.f, ss=0.f;
        #pragma unroll
        for (int i=0;i<48;i++){ s+=v[i]; ss+=v[i]*v[i]; }
        s  += __shfl_xor(s,1);  s  += __shfl_xor(s,2);
        ss += __shfl_xor(ss,1); ss += __shfl_xor(ss,2);
        float mean = s*(1.f/192.f);
        float rstd = rsqrtf(ss*(1.f/192.f) - mean*mean + 1e-5f);
        #pragma unroll
        for (int i8=0;i8<6;i8++){
            bf16x8 pk;
            #pragma unroll
            for (int j=0;j<8;j++){
                int ch = part*48 + i8*8 + j;
                pk[j] = (__bf16)((v[i8*8+j]-mean)*rstd*g2[ch] + b2v[ch]);
            }
            *reinterpret_cast<bf16x8*>(&yb[tok*200 + part*48 + i8*8]) = pk;
        }
    }
    __syncthreads();
    // ---- MLP
    f32x4 acc2[4][3];
    #pragma unroll
    for (int m=0;m<4;m++)
        #pragma unroll
        for (int n=0;n<3;n++) acc2[m][n] = zero4();
    for (int hc=0; hc<4; hc++){
        f32x4 acc1[4][3];
        #pragma unroll
        for (int m=0;m<4;m++)
            #pragma unroll
            for (int n=0;n<3;n++) acc1[m][n] = zero4();
        #pragma unroll
        for (int kc=0; kc<6; kc++){
            int ko = kc*32 + lg*8;
            bf16x8 a[4];
            #pragma unroll
            for (int m=0;m<4;m++) a[m] = ldfrag(&yb[(16*m+lr)*200 + ko]);
            bf16x8 bfr[3];
            #pragma unroll
            for (int n=0;n<3;n++)
                bfr[n] = ldfrag(W1t + (size_t)(hc*192 + 48*w + 16*n + lr)*192 + ko);
            #pragma unroll
            for (int m=0;m<4;m++)
                #pragma unroll
                for (int n=0;n<3;n++) acc1[m][n] = MFMA16(a[m], bfr[n], acc1[m][n]);
        }
        #pragma unroll
        for (int n=0;n<3;n++){
            int jcol = 48*w + 16*n + lr;
            float b1 = fc1b[hc*192 + jcol];
            #pragma unroll
            for (int m=0;m<4;m++)
                #pragma unroll
                for (int r=0;r<4;r++){
                    float xv = acc1[m][n][r] + b1;
                    hb[(16*m + 4*lg + r)*200 + jcol] = (__bf16)gelu_fast(xv);
                }
        }
        __syncthreads();
        #pragma unroll
        for (int kc=0; kc<6; kc++){
            int ko = kc*32 + lg*8;
            bf16x8 a[4];
            #pragma unroll
            for (int m=0;m<4;m++) a[m] = ldfrag(&hb[(16*m+lr)*200 + ko]);
            bf16x8 bfr[3];
            #pragma unroll
            for (int n=0;n<3;n++)
                bfr[n] = ldfrag(W2t + (size_t)(48*w + 16*n + lr)*768 + hc*192 + ko);
            #pragma unroll
            for (int m=0;m<4;m++)
                #pragma unroll
                for (int n=0;n<3;n++) acc2[m][n] = MFMA16(a[m], bfr[n], acc2[m][n]);
        }
        __syncthreads();
    }
    // ---- final: out = acc2 + fc2b + y (scattered pixel write)
    #pragma unroll
    for (int m=0;m<4;m++)
        #pragma unroll
        for (int r=0;r<4;r++){
            int t = 16*m + 4*lg + r;
            int p = wh*8 + (t>>3), q = wwi*8 + (t&7);
            int hh = (p+SSH)&127, w2 = (q+SSH)&127;
            size_t pixb = (((size_t)bb*128 + hh)*128 + w2)*192;
            #pragma unroll
            for (int n=0;n<3;n++){
                int col = 48*w + 16*n + lr;
                out[pixb + col] = acc2[m][n][r] + fc2b[col] + (float)yreg[m][n][r];
            }
        }
}

extern "C" void kernel_launch(void* const* d_in, const int* in_sizes, int n_in,
                              void* d_out, int out_size, void* d_ws, size_t ws_size,
                              hipStream_t stream) {
    const float* x     = (const float*)d_in[0];
    const float* mask  = (const float*)d_in[1];
    const float* n1g   = (const float*)d_in[2];
    const float* n1b   = (const float*)d_in[3];
    const float* qkvw  = (const float*)d_in[4];
    const float* qkvb  = (const float*)d_in[5];
    const float* relt  = (const float*)d_in[6];
    const float* projw = (const float*)d_in[7];
    const float* projb = (const float*)d_in[8];
    const float* n2g   = (const float*)d_in[9];
    const float* n2b   = (const float*)d_in[10];
    const float* fc1w  = (const float*)d_in[11];
    const float* fc1b  = (const float*)d_in[12];
    const float* fc2w  = (const float*)d_in[13];
    const float* fc2b  = (const float*)d_in[14];
    float* out = (float*)d_out;

    char* wsb = (char*)d_ws;
    __bf16* Sb  = (__bf16*)wsb;                        // 150,994,944 B
    __bf16* Bb  = (__bf16*)(wsb + 150994944);          //  50,331,648 B (spatial out)
    __bf16* Fb  = (__bf16*)(wsb + 201326592);          //  50,331,648 B (fourier out)
    __bf16* Wqt = (__bf16*)(wsb + 251658240);          //    221,184 B
    __bf16* Wpt = (__bf16*)(wsb + 251879424);          //     73,728 B
    __bf16* W1t = (__bf16*)(wsb + 251953152);          //    294,912 B
    __bf16* W2t = (__bf16*)(wsb + 252248064);          //    294,912 B
    __bf16* Fre = (__bf16*)(wsb + 252542976);          //      6,144 B
    __bf16* Fim = (__bf16*)(wsb + 252549120);          //      6,144 B
    __bf16* Ci  = (__bf16*)(wsb + 252555264);          //      8,192 B
    __bf16* nSi = (__bf16*)(wsb + 252563456);          //      8,192 B

    k_prep  <<<576,   256, 0, stream>>>(qkvw, projw, fc1w, fc2w, Wqt, Wpt, W1t, W2t,
                                        Fre, Fim, Ci, nSi);
    k_qkv   <<<2048,  256, 0, stream>>>(x, n1g, n1b, Wqt, qkvb, Sb);
    k_attn2 <<<14336, 256, 0, stream>>>(Sb, relt, mask, qkvb, Fre, Fim, Ci, nSi, Bb, Fb);
    k_ffn   <<<2048,  256, 0, stream>>>(Bb, Fb, x, Wpt, projb, n2g, n2b,
                                        W1t, fc1b, W2t, fc2b, out);
}

// Round 20
// 580.266 us; speedup vs baseline: 1.1008x; 1.0269x over previous
//
#include <hip/hip_runtime.h>
#include <hip/hip_bf16.h>
#include <math.h>

#define SSH 4
#define SCALE 0.17677669529663687f  // 1/sqrt(32)

typedef __bf16 bf16x8 __attribute__((ext_vector_type(8)));
typedef __bf16 bf16x4 __attribute__((ext_vector_type(4)));
typedef unsigned short ushort8 __attribute__((ext_vector_type(8)));
typedef float  f32x4  __attribute__((ext_vector_type(4)));

static __device__ __forceinline__ f32x4 mfma16(bf16x8 a, bf16x8 b, f32x4 c){
    return __builtin_amdgcn_mfma_f32_16x16x32_bf16(a, b, c, 0, 0, 0);
}
#define MFMA16(a,b,c) mfma16((a),(b),(c))

static __device__ __forceinline__ bf16x8 ldfrag(const __bf16* p){
    return *reinterpret_cast<const bf16x8*>(p);
}
static __device__ __forceinline__ f32x4 zero4(){
    f32x4 z; z[0]=0.f; z[1]=0.f; z[2]=0.f; z[3]=0.f; return z;
}
// tanh-form GELU via sigmoid identity: 0.5x(1+tanh(u)) == x * sigma(2u)
static __device__ __forceinline__ float gelu_fast(float x){
    float u = x*(0.7978845608f + 0.0356774081f*x*x);
    return __fdividef(x, 1.f + __expf(-2.f*u));
}

// ---------------- K0: weight prep (bf16 [N][K]) + Fourier constant tables ----
__global__ __launch_bounds__(256) void k_prep(const float* __restrict__ qkvw,
        const float* __restrict__ projw, const float* __restrict__ fc1w,
        const float* __restrict__ fc2w, __bf16* __restrict__ Wq,
        __bf16* __restrict__ Wp, __bf16* __restrict__ W1, __bf16* __restrict__ W2,
        __bf16* __restrict__ Fre, __bf16* __restrict__ Fim,
        __bf16* __restrict__ Ci,  __bf16* __restrict__ nSi){
    int i = blockIdx.x*256 + threadIdx.x;
    if (i < 110592){ int n = i/192, k = i - n*192; Wq[i] = (__bf16)qkvw[k*576 + n]; }
    if (i < 36864) { int n = i/192, k = i - n*192; Wp[i] = (__bf16)projw[k*192 + n]; }
    if (i < 147456){ int n = i/192, k = i - n*192; W1[i] = (__bf16)fc1w[k*768 + n]; }
    if (i < 147456){ int n = i/768, k = i - n*768; W2[i] = (__bf16)fc2w[k*192 + n]; }
    if (i < 3072){
        int n = i>>6, p = i&63;
        float vr = 0.f, vi = 0.f;
        if (n < 40){
            int u = n/5, v = n - u*5, r = p>>3, c = p&7;
            int k = (u*r + v*c)&7;
            float ang = (float)k * 0.78539816339744831f;
            vr = cosf(ang)*0.125f; vi = -sinf(ang)*0.125f;
        }
        Fre[i] = (__bf16)vr; Fim[i] = (__bf16)vi;
    }
    if (i < 4096){
        int p = i>>6, n = i&63;
        float vc = 0.f, vs = 0.f;
        if (n < 40){
            int u = n/5, v = n - u*5, r = p>>3, c = p&7;
            int k = (u*r + v*c)&7;
            float ang = (float)k * 0.78539816339744831f;
            float wv = (v>=1 && v<=3)? 2.f : 1.f;
            vc = wv*cosf(ang)*0.125f; vs = -wv*sinf(ang)*0.125f;
        }
        Ci[i] = (__bf16)vc; nSi[i] = (__bf16)vs;
    }
}

// ---------------- K1: LN1 + shift + qkv GEMM (MFMA, staged W + coalesced S) --
__global__ __launch_bounds__(256,2) void k_qkv(const float* __restrict__ x,
        const float* __restrict__ n1g, const float* __restrict__ n1b,
        const __bf16* __restrict__ Wqt, const float* __restrict__ qkv_b,
        __bf16* __restrict__ S){
    __shared__ __align__(16) __bf16 xw[64*200];
    __shared__ __align__(16) __bf16 Wt[192*72];
    __shared__ __align__(16) __bf16 Ss[64*200];
    int tid = threadIdx.x;
    int win = blockIdx.x;
    int bb = win>>8, rem = win&255, wh = rem>>4, wwi = rem&15;
    {
        int tok = tid>>2, part = tid&3;
        int r = tok>>3, c = tok&7;
        int sh = (wh*8 + r + SSH)&127, sw = (wwi*8 + c + SSH)&127;
        const float* srcp = x + (((size_t)(bb*128+sh))*128 + sw)*192 + part*48;
        float v[48];
        #pragma unroll
        for (int i=0;i<12;i++){
            float4 t4 = *reinterpret_cast<const float4*>(srcp + i*4);
            v[i*4]=t4.x; v[i*4+1]=t4.y; v[i*4+2]=t4.z; v[i*4+3]=t4.w;
        }
        float s=0.f, ss=0.f;
        #pragma unroll
        for (int i=0;i<48;i++){ s+=v[i]; ss+=v[i]*v[i]; }
        s  += __shfl_xor(s,1);  s  += __shfl_xor(s,2);
        ss += __shfl_xor(ss,1); ss += __shfl_xor(ss,2);
        float mean = s*(1.f/192.f);
        float rstd = rsqrtf(ss*(1.f/192.f) - mean*mean + 1e-5f);
        #pragma unroll
        for (int i8=0;i8<6;i8++){
            bf16x8 pk;
            #pragma unroll
            for (int j=0;j<8;j++){
                int ch = part*48 + i8*8 + j;
                pk[j] = (__bf16)((v[i8*8+j]-mean)*rstd*n1g[ch] + n1b[ch]);
            }
            *reinterpret_cast<bf16x8*>(&xw[tok*200 + part*48 + i8*8]) = pk;
        }
    }
    int lane = tid&63, w = tid>>6, lr = lane&15, lg = lane>>4;
    ushort8 wreg[6];
    auto ldW = [&](int s, ushort8* wr){
        int nc = s/3, kc = s - nc*3;
        #pragma unroll
        for (int i=0;i<6;i++){
            int e = tid + i*256;
            int j = e>>3, k8 = e&7;
            wr[i] = *reinterpret_cast<const ushort8*>(
                reinterpret_cast<const unsigned short*>(Wqt) + (size_t)(nc*192+j)*192 + kc*64 + k8*8);
        }
    };
    auto stW = [&](ushort8* wr){
        #pragma unroll
        for (int i=0;i<6;i++){
            int e = tid + i*256;
            int j = e>>3, k8 = e&7;
            *reinterpret_cast<ushort8*>(reinterpret_cast<unsigned short*>(Wt) + j*72 + k8*8) = wr[i];
        }
    };
    ldW(0, wreg);
    __syncthreads();
    stW(wreg);
    __syncthreads();
    f32x4 acc[4][3];
    #pragma unroll
    for (int m=0;m<4;m++)
        #pragma unroll
        for (int n=0;n<3;n++) acc[m][n] = zero4();
    for (int s=0; s<9; s++){
        int nc = s/3, kc = s - nc*3;
        if (s<8) ldW(s+1, wreg);
        #pragma unroll
        for (int kk=0; kk<2; kk++){
            int ko = kc*64 + kk*32 + lg*8;
            bf16x8 a[4];
            #pragma unroll
            for (int m=0;m<4;m++) a[m] = ldfrag(&xw[(16*m+lr)*200 + ko]);
            int klo = kk*32 + lg*8;
            bf16x8 bfr[3];
            #pragma unroll
            for (int n=0;n<3;n++) bfr[n] = ldfrag(&Wt[(48*w+16*n+lr)*72 + klo]);
            #pragma unroll
            for (int m=0;m<4;m++)
                #pragma unroll
                for (int n=0;n<3;n++) acc[m][n] = MFMA16(a[m], bfr[n], acc[m][n]);
        }
        if (kc==2){
            #pragma unroll
            for (int n=0;n<3;n++){
                int colL = 48*w + 16*n + lr;
                float bias = qkv_b[nc*192 + colL];
                #pragma unroll
                for (int m=0;m<4;m++)
                    #pragma unroll
                    for (int r=0;r<4;r++){
                        Ss[(16*m + 4*lg + r)*200 + colL] = (__bf16)(acc[m][n][r] + bias);
                        acc[m][n][r] = 0.f;
                    }
            }
        }
        __syncthreads();
        if (kc==2){
            #pragma unroll
            for (int i=0;i<6;i++){
                int e = tid + i*256;
                int row = e/24, c8 = e - row*24;
                *reinterpret_cast<bf16x8*>(S + (size_t)(win*64+row)*576 + nc*192 + c8*8) =
                    *reinterpret_cast<const bf16x8*>(&Ss[row*200 + c8*8]);
            }
        }
        if (s<8) stW(wreg);
        __syncthreads();
    }
}

// ---------------- K2: spatial window attention (MFMA) from S -> Bb (bf16) ----
__global__ __launch_bounds__(256,4) void k_spatial(const __bf16* __restrict__ S,
        const float* __restrict__ relt, const float* __restrict__ mask,
        __bf16* __restrict__ Bb){
    __shared__ __align__(16) __bf16 P[64*72];
    __shared__ __align__(16) __bf16 Vt[32*72];
    __shared__ float reltL[1350];
    int tid = threadIdx.x;
    int win = blockIdx.x;
    int widx = win & 255;
    int lane = tid&63, w = tid>>6, lr = lane&15, lg = lane>>4;
    for (int e=tid; e<1350; e+=256) reltL[e] = relt[e];
    float mreg[16];
    int bidx[16];
    #pragma unroll
    for (int nt=0; nt<4; nt++)
        #pragma unroll
        for (int r=0;r<4;r++){
            int row = 16*w + 4*lg + r;
            int col = 16*nt + lr;
            mreg[nt*4+r] = mask[((widx*64 + row)<<6) + col];
            int dr = (row>>3)-(col>>3)+7, dc = (row&7)-(col&7)+7;
            bidx[nt*4+r] = (dr*15+dc)*6;
        }
    const size_t sbase = (size_t)win*64*576;
    const __bf16* Sq = S + sbase;
    const __bf16* Sk = S + sbase + 192;
    const __bf16* Sv = S + sbase + 384;
    for (int h=0; h<6; h++){
        __syncthreads();
        {
            int d = tid&31, pg = tid>>5;
            const __bf16* sp = Sv + (size_t)(pg*8)*576 + h*32 + d;
            bf16x4 v0, v1;
            v0[0]=sp[0];    v0[1]=sp[576];  v0[2]=sp[1152]; v0[3]=sp[1728];
            v1[0]=sp[2304]; v1[1]=sp[2880]; v1[2]=sp[3456]; v1[3]=sp[4032];
            *reinterpret_cast<bf16x4*>(&Vt[d*72 + pg*8])   = v0;
            *reinterpret_cast<bf16x4*>(&Vt[d*72 + pg*8+4]) = v1;
        }
        __syncthreads();
        bf16x8 aq = ldfrag(Sq + (size_t)(16*w+lr)*576 + h*32 + lg*8);
        f32x4 acc[4];
        #pragma unroll
        for (int nt=0;nt<4;nt++){
            bf16x8 bk = ldfrag(Sk + (size_t)(16*nt+lr)*576 + h*32 + lg*8);
            acc[nt] = MFMA16(aq, bk, zero4());
        }
        float p[16];
        #pragma unroll
        for (int r=0;r<4;r++){
            float sc[4];
            #pragma unroll
            for (int nt=0;nt<4;nt++)
                sc[nt] = acc[nt][r]*SCALE + reltL[bidx[nt*4+r] + h] + mreg[nt*4+r];
            float mx = fmaxf(fmaxf(sc[0],sc[1]),fmaxf(sc[2],sc[3]));
            mx = fmaxf(mx, __shfl_xor(mx,1));
            mx = fmaxf(mx, __shfl_xor(mx,2));
            mx = fmaxf(mx, __shfl_xor(mx,4));
            mx = fmaxf(mx, __shfl_xor(mx,8));
            float sum = 0.f;
            #pragma unroll
            for (int nt=0;nt<4;nt++){ sc[nt] = __expf(sc[nt]-mx); sum += sc[nt]; }
            sum += __shfl_xor(sum,1);
            sum += __shfl_xor(sum,2);
            sum += __shfl_xor(sum,4);
            sum += __shfl_xor(sum,8);
            float inv = 1.f/sum;
            #pragma unroll
            for (int nt=0;nt<4;nt++) p[r*4+nt] = sc[nt]*inv;
        }
        #pragma unroll
        for (int r=0;r<4;r++)
            #pragma unroll
            for (int nt=0;nt<4;nt++)
                P[(16*w + 4*lg + r)*72 + 16*nt + lr] = (__bf16)p[r*4+nt];
        #pragma unroll
        for (int dt=0; dt<2; dt++){
            f32x4 o = zero4();
            #pragma unroll
            for (int ks=0; ks<2; ks++)
                o = MFMA16(ldfrag(&P[(16*w+lr)*72 + ks*32 + lg*8]),
                           ldfrag(&Vt[(16*dt+lr)*72 + ks*32 + lg*8]), o);
            #pragma unroll
            for (int r=0;r<4;r++){
                int row = 16*w + 4*lg + r;
                Bb[((size_t)win*64 + row)*192 + h*32 + 16*dt + lr] = (__bf16)o[r];
            }
        }
    }
}

// ------- K3: Fourier branch, fully MFMA, merged phases; bf16 RMW into Bb -----
__global__ __launch_bounds__(256,3) void k_fattn(const __bf16* __restrict__ S,
        const float* __restrict__ qkv_b,
        const __bf16* __restrict__ Fre_g, const __bf16* __restrict__ Fim_g,
        const __bf16* __restrict__ Ci_g,  const __bf16* __restrict__ nSi_g,
        __bf16* __restrict__ Bb){
    __shared__ __align__(16) unsigned char arena[51968];
    __bf16* Gq_r = (__bf16*)(arena);             // [48][40]
    __bf16* Gqin = (__bf16*)(arena + 3840);      // [48][40] (negated Qi)
    __bf16* Gk_r = (__bf16*)(arena + 7680);      // [48][40]
    __bf16* Gk_i = (__bf16*)(arena + 11520);     // [48][40]
    __bf16* Rt_r = (__bf16*)(arena);             // [32][88] overlay (PV phase)
    __bf16* Rt_i = (__bf16*)(arena + 5632);      // [32][88]
    __bf16* Gv_r = (__bf16*)(arena + 15360);     // [32][88]
    __bf16* Gv_i = (__bf16*)(arena + 20992);     // [32][88]
    __bf16* St3  = (__bf16*)(arena + 26624);     // [3][32][88] (spectra phase)
    float*  Smat = (float*) (arena + 26624);     // [48][52] overlay (QK phase)
    __bf16* P    = (__bf16*)(arena + 43520);     // [48][88]
    int tid = threadIdx.x;
    int win = blockIdx.x / 6, h = blockIdx.x - win*6;
    int lane = tid&63, w = tid>>6, lr = lane&15, lg = lane>>4;
    bf16x4 z4; z4[0]=z4[1]=z4[2]=z4[3]=(__bf16)0.f;
    const size_t sbase = (size_t)win*64*576 + h*32;
    {
        int t2 = tid & 127;
        __bf16* A = (tid<128)? Gv_r : Gv_i;
        int row = t2>>2, c4 = (t2&3)*4;
        *reinterpret_cast<bf16x4*>(A + row*88 + 48 + c4) = z4;
    }
    {
        int d = tid&31, pg = tid>>5;
        #pragma unroll
        for (int m=0;m<3;m++){
            const __bf16* sp = S + sbase + (size_t)m*192 + (size_t)pg*8*576 + d;
            bf16x4 v0, v1;
            v0[0]=sp[0];      v0[1]=sp[576];    v0[2]=sp[1152];   v0[3]=sp[1728];
            v1[0]=sp[2304];   v1[1]=sp[2880];   v1[2]=sp[3456];   v1[3]=sp[4032];
            *reinterpret_cast<bf16x4*>(&St3[m*2816 + d*88 + pg*8])     = v0;
            *reinterpret_cast<bf16x4*>(&St3[m*2816 + d*88 + pg*8 + 4]) = v1;
        }
    }
    __syncthreads();
    for (int j=w; j<36; j+=4){
        int m = j/12, jj = j - m*12;
        int term = jj/6, r2 = jj - term*6;
        const __bf16* Stm = &St3[m*2816];
        if (m<2){
            int mt = r2>>1, nt = r2&1;
            const __bf16* Ag = (term? Fim_g : Fre_g) + (16*mt+lr)*64 + lg*8;
            f32x4 acc = zero4();
            acc = MFMA16(*reinterpret_cast<const bf16x8*>(Ag),
                         ldfrag(&Stm[(16*nt+lr)*88 + lg*8]), acc);
            acc = MFMA16(*reinterpret_cast<const bf16x8*>(Ag+32),
                         ldfrag(&Stm[(16*nt+lr)*88 + 32 + lg*8]), acc);
            int d = 16*nt + lr;
            float b = qkv_b[m*192 + h*32 + d];
            __bf16* dst = (m==0)? (term? Gqin : Gq_r) : (term? Gk_i : Gk_r);
            #pragma unroll
            for (int r=0;r<4;r++){
                int n = 16*mt + 4*lg + r;
                float val = acc[r] + ((term==0) ? ((n==0)? -7.f*b : b) : b);
                if (m==0 && term==1) val = -val;     // store -Qi
                dst[n*40 + d] = (__bf16)val;
            }
        } else {
            int mt = r2/3, nt = r2 - mt*3;
            const __bf16* Bg = (term? Fim_g : Fre_g) + (16*nt+lr)*64 + lg*8;
            f32x4 acc = zero4();
            acc = MFMA16(ldfrag(&Stm[(16*mt+lr)*88 + lg*8]),
                         *reinterpret_cast<const bf16x8*>(Bg), acc);
            acc = MFMA16(ldfrag(&Stm[(16*mt+lr)*88 + 32 + lg*8]),
                         *reinterpret_cast<const bf16x8*>(Bg+32), acc);
            int n = 16*nt + lr;
            __bf16* dst = term? Gv_i : Gv_r;
            #pragma unroll
            for (int r=0;r<4;r++){
                int d = 16*mt + 4*lg + r;
                float b = qkv_b[2*192 + h*32 + d];
                float val = acc[r] + ((term==0) ? ((n==0)? -7.f*b : b) : b);
                dst[d*88 + n] = (__bf16)val;
            }
        }
    }
    __syncthreads();
    for (int j=w; j<9; j+=4){
        int mt = j/3, nt = j - mt*3;
        bf16x8 qr = ldfrag(&Gq_r[(16*mt+lr)*40 + lg*8]);
        bf16x8 qi = ldfrag(&Gqin[(16*mt+lr)*40 + lg*8]);
        bf16x8 kr = ldfrag(&Gk_r[(16*nt+lr)*40 + lg*8]);
        bf16x8 ki = ldfrag(&Gk_i[(16*nt+lr)*40 + lg*8]);
        f32x4 sre = MFMA16(qi, ki, zero4());   // (-Qi).Ki
        sre = MFMA16(qr, kr, sre);             // + Qr.Kr
        f32x4 t1 = MFMA16(qr, ki, zero4());    // Qr.Ki
        f32x4 t2 = MFMA16(qi, kr, zero4());    // (-Qi).Kr
        #pragma unroll
        for (int r=0;r<4;r++){
            float sim = t1[r] - t2[r];
            Smat[(16*mt + 4*lg + r)*52 + 16*nt + lr] =
                SCALE * sqrtf(sre[r]*sre[r] + sim*sim);
        }
    }
    __syncthreads();
    if (tid < 160){
        int row = tid>>2, part = tid&3, e0 = part*10;
        float mx = -1e30f;
        #pragma unroll
        for (int j=0;j<10;j++) mx = fmaxf(mx, Smat[row*52 + e0 + j]);
        mx = fmaxf(mx, __shfl_xor(mx,1));
        mx = fmaxf(mx, __shfl_xor(mx,2));
        float ex[10]; float sum=0.f;
        #pragma unroll
        for (int j=0;j<10;j++){ ex[j] = __expf(Smat[row*52+e0+j]-mx); sum += ex[j]; }
        sum += __shfl_xor(sum,1);
        sum += __shfl_xor(sum,2);
        float inv = 1.f/sum;
        #pragma unroll
        for (int j=0;j<10;j++) Smat[row*52+e0+j] = ex[j]*inv;
    }
    __syncthreads();
    for (int e=tid; e<3072; e+=256){
        int row = e>>6, col = e&63;
        float v = (row<40 && col<40)? Smat[row*52+col] : 0.f;
        P[row*88+col] = (__bf16)v;
    }
    {
        int t2 = tid & 127;
        __bf16* A = (tid<128)? Rt_r : Rt_i;
        int row = t2>>2, c4 = (t2&3)*4;
        *reinterpret_cast<bf16x4*>(A + row*88 + 48 + c4) = z4;
    }
    __syncthreads();
    for (int j=w; j<12; j+=4){
        int term = j/6, r2 = j - term*6;
        int dt = r2/3, nt = r2 - dt*3;
        const __bf16* Gv = term? Gv_i : Gv_r;
        f32x4 acc = zero4();
        #pragma unroll
        for (int ks=0; ks<2; ks++)
            acc = MFMA16(ldfrag(&Gv[(16*dt+lr)*88 + ks*32 + lg*8]),
                         ldfrag(&P [(16*nt+lr)*88 + ks*32 + lg*8]), acc);
        __bf16* dst = term? Rt_i : Rt_r;
        #pragma unroll
        for (int r=0;r<4;r++)
            dst[(16*dt + 4*lg + r)*88 + 16*nt + lr] = (__bf16)acc[r];
    }
    __syncthreads();
    for (int j=w; j<8; j+=4){
        int dt = j>>2, pt = j&3;
        f32x4 acc = zero4();
        #pragma unroll
        for (int ks=0; ks<2; ks++)
            acc = MFMA16(*reinterpret_cast<const bf16x8*>(nSi_g + (16*pt+lr)*64 + ks*32 + lg*8),
                         ldfrag(&Rt_i[(16*dt+lr)*88 + ks*32 + lg*8]), acc);
        #pragma unroll
        for (int ks=0; ks<2; ks++)
            acc = MFMA16(*reinterpret_cast<const bf16x8*>(Ci_g + (16*pt+lr)*64 + ks*32 + lg*8),
                         ldfrag(&Rt_r[(16*dt+lr)*88 + ks*32 + lg*8]), acc);
        #pragma unroll
        for (int r=0;r<4;r++){
            int p = 16*pt + 4*lg + r, d = 16*dt + lr;
            size_t idx = ((size_t)win*64 + p)*192 + h*32 + d;   // disjoint per (win,h)
            Bb[idx] = (__bf16)((float)Bb[idx] + acc[r]);
        }
    }
}

// ------- K4: fused FFN: proj + residual + LN2 + fc1 + GELU + fc2 + residual --
__global__ __launch_bounds__(256,2) void k_ffn(const __bf16* __restrict__ Bb,
        const float* __restrict__ x, const __bf16* __restrict__ Wpt,
        const float* __restrict__ proj_b, const float* __restrict__ g2,
        const float* __restrict__ b2v, const __bf16* __restrict__ W1t,
        const float* __restrict__ fc1b, const __bf16* __restrict__ W2t,
        const float* __restrict__ fc2b, float* __restrict__ out){
    __shared__ __align__(16) __bf16 hb[64*200];   // hbuf
    __shared__ __align__(16) __bf16 yb[64*200];   // y bf16 -> xln (in-place)
    int tid = threadIdx.x;
    int win = blockIdx.x;
    int lane = tid&63, w = tid>>6, lr = lane&15, lg = lane>>4;
    // ---- proj MFMA, A direct from global bf16 Bb
    const __bf16* Ab = Bb + (size_t)win*64*192;
    f32x4 acc[4][3];
    #pragma unroll
    for (int m=0;m<4;m++)
        #pragma unroll
        for (int n=0;n<3;n++) acc[m][n] = zero4();
    #pragma unroll
    for (int kc=0; kc<6; kc++){
        int ko = kc*32 + lg*8;
        bf16x8 a[4];
        #pragma unroll
        for (int m=0;m<4;m++) a[m] = ldfrag(Ab + (size_t)(16*m+lr)*192 + ko);
        bf16x8 bfr[3];
        #pragma unroll
        for (int n=0;n<3;n++)
            bfr[n] = ldfrag(Wpt + (size_t)(48*w + 16*n + lr)*192 + ko);
        #pragma unroll
        for (int m=0;m<4;m++)
            #pragma unroll
            for (int n=0;n<3;n++) acc[m][n] = MFMA16(a[m], bfr[n], acc[m][n]);
    }
    // ---- y = proj + bias + x (residual); bf16 copy in regs + LDS tile
    int bb = win>>8, rem = win&255, wh = rem>>4, wwi = rem&15;
    bf16x4 yreg[4][3];
    #pragma unroll
    for (int m=0;m<4;m++)
        #pragma unroll
        for (int r=0;r<4;r++){
            int t = 16*m + 4*lg + r;
            int p = wh*8 + (t>>3), q = wwi*8 + (t&7);
            int hh = (p+SSH)&127, w2 = (q+SSH)&127;
            size_t pixb = (((size_t)bb*128 + hh)*128 + w2)*192;
            #pragma unroll
            for (int n=0;n<3;n++){
                int col = 48*w + 16*n + lr;
                float yv = acc[m][n][r] + proj_b[col] + x[pixb + col];
                __bf16 yh = (__bf16)yv;
                yreg[m][n][r] = yh;
                yb[t*200 + col] = yh;
            }
        }
    __syncthreads();
    // ---- LN2 in-place on yb
    {
        int tok = tid>>2, part = tid&3;
        float v[48];
        #pragma unroll
        for (int i8=0;i8<6;i8++){
            bf16x8 pk = *reinterpret_cast<const bf16x8*>(&yb[tok*200 + part*48 + i8*8]);
            #pragma unroll
            for (int j=0;j<8;j++) v[i8*8+j] = (float)pk[j];
        }
        float s=0.f, ss=0.f;
        #pragma unroll
        for (int i=0;i<48;i++){ s+=v[i]; ss+=v[i]*v[i]; }
        s  += __shfl_xor(s,1);  s  += __shfl_xor(s,2);
        ss += __shfl_xor(ss,1); ss += __shfl_xor(ss,2);
        float mean = s*(1.f/192.f);
        float rstd = rsqrtf(ss*(1.f/192.f) - mean*mean + 1e-5f);
        #pragma unroll
        for (int i8=0;i8<6;i8++){
            bf16x8 pk;
            #pragma unroll
            for (int j=0;j<8;j++){
                int ch = part*48 + i8*8 + j;
                pk[j] = (__bf16)((v[i8*8+j]-mean)*rstd*g2[ch] + b2v[ch]);
            }
            *reinterpret_cast<bf16x8*>(&yb[tok*200 + part*48 + i8*8]) = pk;
        }
    }
    __syncthreads();
    // ---- MLP
    f32x4 acc2[4][3];
    #pragma unroll
    for (int m=0;m<4;m++)
        #pragma unroll
        for (int n=0;n<3;n++) acc2[m][n] = zero4();
    for (int hc=0; hc<4; hc++){
        f32x4 acc1[4][3];
        #pragma unroll
        for (int m=0;m<4;m++)
            #pragma unroll
            for (int n=0;n<3;n++) acc1[m][n] = zero4();
        #pragma unroll
        for (int kc=0; kc<6; kc++){
            int ko = kc*32 + lg*8;
            bf16x8 a[4];
            #pragma unroll
            for (int m=0;m<4;m++) a[m] = ldfrag(&yb[(16*m+lr)*200 + ko]);
            bf16x8 bfr[3];
            #pragma unroll
            for (int n=0;n<3;n++)
                bfr[n] = ldfrag(W1t + (size_t)(hc*192 + 48*w + 16*n + lr)*192 + ko);
            #pragma unroll
            for (int m=0;m<4;m++)
                #pragma unroll
                for (int n=0;n<3;n++) acc1[m][n] = MFMA16(a[m], bfr[n], acc1[m][n]);
        }
        #pragma unroll
        for (int n=0;n<3;n++){
            int jcol = 48*w + 16*n + lr;
            float b1 = fc1b[hc*192 + jcol];
            #pragma unroll
            for (int m=0;m<4;m++)
                #pragma unroll
                for (int r=0;r<4;r++){
                    float xv = acc1[m][n][r] + b1;
                    hb[(16*m + 4*lg + r)*200 + jcol] = (__bf16)gelu_fast(xv);
                }
        }
        __syncthreads();
        #pragma unroll
        for (int kc=0; kc<6; kc++){
            int ko = kc*32 + lg*8;
            bf16x8 a[4];
            #pragma unroll
            for (int m=0;m<4;m++) a[m] = ldfrag(&hb[(16*m+lr)*200 + ko]);
            bf16x8 bfr[3];
            #pragma unroll
            for (int n=0;n<3;n++)
                bfr[n] = ldfrag(W2t + (size_t)(48*w + 16*n + lr)*768 + hc*192 + ko);
            #pragma unroll
            for (int m=0;m<4;m++)
                #pragma unroll
                for (int n=0;n<3;n++) acc2[m][n] = MFMA16(a[m], bfr[n], acc2[m][n]);
        }
        __syncthreads();
    }
    // ---- final: out = acc2 + fc2b + y (scattered pixel write)
    #pragma unroll
    for (int m=0;m<4;m++)
        #pragma unroll
        for (int r=0;r<4;r++){
            int t = 16*m + 4*lg + r;
            int p = wh*8 + (t>>3), q = wwi*8 + (t&7);
            int hh = (p+SSH)&127, w2 = (q+SSH)&127;
            size_t pixb = (((size_t)bb*128 + hh)*128 + w2)*192;
            #pragma unroll
            for (int n=0;n<3;n++){
                int col = 48*w + 16*n + lr;
                out[pixb + col] = acc2[m][n][r] + fc2b[col] + (float)yreg[m][n][r];
            }
        }
}

extern "C" void kernel_launch(void* const* d_in, const int* in_sizes, int n_in,
                              void* d_out, int out_size, void* d_ws, size_t ws_size,
                              hipStream_t stream) {
    const float* x     = (const float*)d_in[0];
    const float* mask  = (const float*)d_in[1];
    const float* n1g   = (const float*)d_in[2];
    const float* n1b   = (const float*)d_in[3];
    const float* qkvw  = (const float*)d_in[4];
    const float* qkvb  = (const float*)d_in[5];
    const float* relt  = (const float*)d_in[6];
    const float* projw = (const float*)d_in[7];
    const float* projb = (const float*)d_in[8];
    const float* n2g   = (const float*)d_in[9];
    const float* n2b   = (const float*)d_in[10];
    const float* fc1w  = (const float*)d_in[11];
    const float* fc1b  = (const float*)d_in[12];
    const float* fc2w  = (const float*)d_in[13];
    const float* fc2b  = (const float*)d_in[14];
    float* out = (float*)d_out;

    char* wsb = (char*)d_ws;
    __bf16* Sb  = (__bf16*)wsb;                        // 150,994,944 B
    __bf16* Bb  = (__bf16*)(wsb + 150994944);          //  50,331,648 B (bf16 attn out)
    __bf16* Wqt = (__bf16*)(wsb + 251658240);          //    221,184 B
    __bf16* Wpt = (__bf16*)(wsb + 251879424);          //     73,728 B
    __bf16* W1t = (__bf16*)(wsb + 251953152);          //    294,912 B
    __bf16* W2t = (__bf16*)(wsb + 252248064);          //    294,912 B
    __bf16* Fre = (__bf16*)(wsb + 252542976);          //      6,144 B
    __bf16* Fim = (__bf16*)(wsb + 252549120);          //      6,144 B
    __bf16* Ci  = (__bf16*)(wsb + 252555264);          //      8,192 B
    __bf16* nSi = (__bf16*)(wsb + 252563456);          //      8,192 B

    k_prep   <<<576,   256, 0, stream>>>(qkvw, projw, fc1w, fc2w, Wqt, Wpt, W1t, W2t,
                                         Fre, Fim, Ci, nSi);
    k_qkv    <<<2048,  256, 0, stream>>>(x, n1g, n1b, Wqt, qkvb, Sb);
    k_spatial<<<2048,  256, 0, stream>>>(Sb, relt, mask, Bb);
    k_fattn  <<<12288, 256, 0, stream>>>(Sb, qkvb, Fre, Fim, Ci, nSi, Bb);
    k_ffn    <<<2048,  256, 0, stream>>>(Bb, x, Wpt, projb, n2g, n2b,
                                         W1t, fc1b, W2t, fc2b, out);
}